// Round 5
// baseline (138.786 us; speedup 1.0000x reference)
//
#include <hip/hip_runtime.h>
#include <hip/hip_bf16.h>

// DiffusionGraphConv on MI355X (gfx950), bf16 MFMA pipeline, round 5.
//
// Pipeline (4 launches):
//   prep (fused): cvt_sup | sup_t(from f32) | w2t | pack
//   psq  (128x32 2-phase GEMM): Pstack = [A1; 2A1^2-I; A2; 2A2^2-I]
//   big  (256^2 8-phase GEMM, REWORKED schedule): Y = Pstack @ X0
//   final(128x128 2-phase GEMM): out = [X0|Y] @ W2 + bias
//
// 8-phase rework vs round 3: group-aligned staging.  Group t = 4 phases
// reading K-tile t from buf(t&1).  Phases 0,1 of group t stage ALL 4
// half-tiles of K-tile t+1 into the other buffer (free since the group
// boundary).  ONE vmcnt(0) at group end: those loads are then 2.5-3.5
// phases (~400-550cy) old -> wait nearly free (L2-resident).  R3's bug:
// vmcnt(4) mid-group forced loads issued 0-1 phases earlier -> ~70% idle.
//
// ws layout (bf16 elems):
//   PSTK 4M | SUPT 2M | X0T 8M | X0NF 8M | XNF 32M | W2T 80K

typedef short bf16x8  __attribute__((ext_vector_type(8)));
typedef short short4v __attribute__((ext_vector_type(4)));
typedef float f32x4   __attribute__((ext_vector_type(4)));

constexpr size_t MB1    = 1024ull * 1024ull;
constexpr size_t SZ_MAT = 8192ull * 1024ull;
constexpr size_t OFF_PSTK = 0;
constexpr size_t OFF_SUPT = 4 * MB1;
constexpr size_t OFF_X0T  = 6 * MB1;
constexpr size_t OFF_X0NF = OFF_X0T  + SZ_MAT;
constexpr size_t OFF_XNF  = OFF_X0NF + SZ_MAT;
constexpr size_t OFF_W2T  = OFF_XNF  + 4 * SZ_MAT;

__device__ __forceinline__ unsigned short f2bf(float x) {
  union { float f; unsigned int u; } v; v.f = x;
  unsigned int r = v.u + 0x7fffu + ((v.u >> 16) & 1u);   // RNE
  return (unsigned short)(r >> 16);
}

#define GLD16(gp, lp)                                                         \
  __builtin_amdgcn_global_load_lds(                                           \
      (const __attribute__((address_space(1))) unsigned int*)(gp),            \
      (__attribute__((address_space(3))) unsigned int*)(lp), 16, 0, 0)

__device__ __forceinline__ bf16x8 dsr128(unsigned byteaddr) {
  bf16x8 r;
  asm volatile("ds_read_b128 %0, %1" : "=v"(r) : "v"(byteaddr));
  return r;
}

// ---------------- fused prep kernel (unchanged from round 4) --------------

__global__ __launch_bounds__(256)
void prep_kernel(const float* __restrict__ sup,
                 const float* __restrict__ weight,
                 const float* __restrict__ inputs,
                 const float* __restrict__ state,
                 unsigned short* __restrict__ ws) {
  __shared__ unsigned short tile[64][65];
  int bid = blockIdx.x;
  int tl  = threadIdx.x;

  if (bid < 2048) {                       // ---- cvt_sup
    size_t t = (size_t)bid * 256 + tl;
    const float4* src = (const float4*)sup;
    float4 v = src[t];
    size_t e = t * 4;
    size_t s = e >> 20;
    size_t r = e & (MB1 - 1);
    short4v o; o[0] = (short)f2bf(v.x); o[1] = (short)f2bf(v.y);
    o[2] = (short)f2bf(v.z); o[3] = (short)f2bf(v.w);
    *(short4v*)&ws[OFF_PSTK + 2 * s * MB1 + r] = o;
  } else if (bid < 2560) {                // ---- sup_t (from f32 source)
    int i = bid - 2048;
    int nt = i & 15, mt = (i >> 4) & 15, s = i >> 8;
    const float* A = sup + (size_t)s * MB1;
    unsigned short* AT = ws + OFF_SUPT + (size_t)s * MB1;
    int cl = tl & 63, rg = tl >> 6;
#pragma unroll 4
    for (int rr = 0; rr < 16; ++rr) {
      int rl = rr * 4 + rg;
      tile[rl][cl] = f2bf(A[(size_t)(nt * 64 + rl) * 1024 + mt * 64 + cl]);
    }
    __syncthreads();
#pragma unroll 4
    for (int rr = 0; rr < 16; ++rr) {
      int ml = rr * 4 + rg;
      AT[(size_t)(mt * 64 + ml) * 1024 + nt * 64 + cl] = tile[cl][ml];
    }
  } else if (bid < 2880) {                // ---- w2t
    int t = (bid - 2560) * 256 + tl;
    int o = t / 640, k = t % 640;
    int m = k >> 7, f = k & 127;
    ws[OFF_W2T + t] = f2bf(weight[(f * 5 + m) * 128 + o]);
  } else {                                // ---- pack
    int i = bid - 2880;
    int b = i & 63, nt = (i >> 6) & 15, ft = i >> 10;
    const float* src = ft ? state : inputs;
    unsigned short* x0t  = ws + OFF_X0T;
    unsigned short* x0nf = ws + OFF_X0NF;
    int fl = tl & 63, nr = tl >> 6;
#pragma unroll 4
    for (int rr = 0; rr < 16; ++rr) {
      int n_loc = rr * 4 + nr;
      float v = src[(size_t)b * 65536 + (size_t)(nt * 64 + n_loc) * 64 + fl];
      unsigned short bv = f2bf(v);
      tile[n_loc][fl] = bv;
      x0nf[(size_t)(nt * 64 + n_loc) * 8192 + b * 128 + ft * 64 + fl] = bv;
    }
    __syncthreads();
#pragma unroll 4
    for (int rr = 0; rr < 16; ++rr) {
      int f_loc = rr * 4 + nr;
      x0t[(size_t)(b * 128 + ft * 64 + f_loc) * 1024 + nt * 64 + fl] =
          tile[fl][f_loc];
    }
  }
}

// ---------------- 256^2 8-phase GEMM (big) ----------------
// BM=BN=256, BK=64, 512 thr (8 waves 2x4), wave tile 128x64 (8x4 frags).
// LDS 128KB: buf{0,1} x { A 32KB | B 32KB }, 16B-granule XOR swizzle.

#define PHASE(Q, BUF, STAGE, VM)                                              \
  {                                                                           \
    if ((Q) == 0) {                                                           \
      _Pragma("unroll")                                                       \
      for (int j = 0; j < 4; ++j) {                                           \
        bfr[j][0] = dsr128(bbase + (BUF)*65536u + j*2048u + gk0);             \
        bfr[j][1] = dsr128(bbase + (BUF)*65536u + j*2048u + gk1);             \
      }                                                                       \
    }                                                                         \
    bf16x8 af0k0 = dsr128(abase + (BUF)*65536u + ((Q)*2+0)*2048u + gk0);      \
    bf16x8 af0k1 = dsr128(abase + (BUF)*65536u + ((Q)*2+0)*2048u + gk1);      \
    bf16x8 af1k0 = dsr128(abase + (BUF)*65536u + ((Q)*2+1)*2048u + gk0);      \
    bf16x8 af1k1 = dsr128(abase + (BUF)*65536u + ((Q)*2+1)*2048u + gk1);      \
    STAGE;                                                                    \
    __builtin_amdgcn_sched_barrier(0);                                        \
    __builtin_amdgcn_s_barrier();                                             \
    asm volatile("s_waitcnt lgkmcnt(0)" ::: "memory");                        \
    __builtin_amdgcn_sched_barrier(0);                                        \
    __builtin_amdgcn_s_setprio(1);                                            \
    _Pragma("unroll")                                                         \
    for (int j = 0; j < 4; ++j) {                                             \
      acc[(Q)*2+0][j] = __builtin_amdgcn_mfma_f32_16x16x32_bf16(              \
          af0k0, bfr[j][0], acc[(Q)*2+0][j], 0, 0, 0);                        \
      acc[(Q)*2+1][j] = __builtin_amdgcn_mfma_f32_16x16x32_bf16(              \
          af1k0, bfr[j][0], acc[(Q)*2+1][j], 0, 0, 0);                        \
    }                                                                         \
    _Pragma("unroll")                                                         \
    for (int j = 0; j < 4; ++j) {                                             \
      acc[(Q)*2+0][j] = __builtin_amdgcn_mfma_f32_16x16x32_bf16(              \
          af0k1, bfr[j][1], acc[(Q)*2+0][j], 0, 0, 0);                        \
      acc[(Q)*2+1][j] = __builtin_amdgcn_mfma_f32_16x16x32_bf16(              \
          af1k1, bfr[j][1], acc[(Q)*2+1][j], 0, 0, 0);                        \
    }                                                                         \
    __builtin_amdgcn_s_setprio(0);                                            \
    __builtin_amdgcn_sched_barrier(0);                                        \
    if (VM) { asm volatile("s_waitcnt vmcnt(0)" ::: "memory"); }              \
    __builtin_amdgcn_s_barrier();                                             \
    __builtin_amdgcn_sched_barrier(0);                                        \
  }

// Group t: 4 phases reading buf(BUF); phases 0,1 stage K-tile t+1 into
// buf(BUF^1); one vmcnt(0) at phase 3 (loads then >=2.5 phases old).
#define GROUP(T, BUF, EN)                                                     \
  PHASE(0, BUF, if (EN) stageA2((BUF) ^ 1, (T) + 1), 0)                       \
  PHASE(1, BUF, if (EN) stageB2((BUF) ^ 1, (T) + 1), 0)                       \
  PHASE(2, BUF, , 0)                                                          \
  PHASE(3, BUF, , 1)

__global__ __launch_bounds__(512, 2)
void gemm8_kernel(unsigned short* __restrict__ ws) {
  extern __shared__ unsigned short lds[];   // 131072 B via launch config

  const unsigned short* Aop = ws + OFF_PSTK;   // [4096][1024]
  const unsigned short* Bop = ws + OFF_X0T;    // [8192][1024] (B^T layout)
  unsigned short* Y = ws + OFF_XNF;            // [4096][8192]

  const int tid = threadIdx.x;
  const int l  = tid & 63, w = tid >> 6;
  const int wr = w >> 2, wc = w & 3;
  const int lm = l & 15, kq = l >> 4;

  // grid 512 = 16 bm x 32 bn; 8x8 tile rectangle per XCD.
  int bid = blockIdx.x;
  int xcd = bid & 7, idx = bid >> 3;
  int bm = ((xcd & 1) << 3) | (idx & 7);
  int bn = ((xcd >> 1) << 3) | (idx >> 3);

  const size_t a_row0 = (size_t)bm * 256;
  const size_t b_row0 = (size_t)bn * 256;

  // staging constants: half-tile = 128 rows x 64k; chunk (c*8+w) = 8 rows.
  const int rl = l >> 3;                 // 0..7 == rowloc&7
  const int kg = (l & 7) ^ rl;           // pre-swizzled source granule

  // ds-read constants
  const unsigned LB =
      (unsigned)(unsigned long long)(__attribute__((address_space(3)))
                                         const unsigned short*)lds;
  const unsigned gk0 = 16u * (unsigned)(kq ^ (lm & 7));
  const unsigned gk1 = gk0 ^ 64u;
  const unsigned abase = LB + (unsigned)((wr * 128 + lm) * 128);
  const unsigned bbase = LB + 32768u + (unsigned)((wc * 64 + lm) * 128);

  auto stageA2 = [&](int buf, int kt) {
#pragma unroll
    for (int h = 0; h < 2; ++h)
#pragma unroll
      for (int c = 0; c < 2; ++c) {
        int rloc = (c * 8 + w) * 8 + rl;
        const unsigned short* gp =
            Aop + ((a_row0 + h * 128 + rloc) << 10) + kt * 64 + kg * 8;
        GLD16(gp, &lds[buf * 32768 + h * 8192 + (c * 8 + w) * 512]);
      }
  };
  auto stageB2 = [&](int buf, int kt) {
#pragma unroll
    for (int h = 0; h < 2; ++h)
#pragma unroll
      for (int c = 0; c < 2; ++c) {
        int rloc = (c * 8 + w) * 8 + rl;
        const unsigned short* gp =
            Bop + ((b_row0 + h * 128 + rloc) << 10) + kt * 64 + kg * 8;
        GLD16(gp, &lds[buf * 32768 + 16384 + h * 8192 + (c * 8 + w) * 512]);
      }
  };

  f32x4 acc[8][4] = {};
  bf16x8 bfr[4][2];

  // prologue: K-tile 0 fully into buf0
  stageA2(0, 0); stageB2(0, 0);
  asm volatile("s_waitcnt vmcnt(0)" ::: "memory");
  __builtin_amdgcn_s_barrier();
  __builtin_amdgcn_sched_barrier(0);

  for (int u = 0; u < 7; ++u) {
    int t0 = 2 * u;
    GROUP(t0, 0, 1)
    GROUP(t0 + 1, 1, 1)
  }
  GROUP(14, 0, 1)
  GROUP(15, 1, 0)

  // epilogue: Y bf16
#pragma unroll
  for (int i = 0; i < 8; ++i) {
    int rg0 = bm * 256 + wr * 128 + i * 16 + kq * 4;
#pragma unroll
    for (int j = 0; j < 4; ++j) {
      int cg = bn * 256 + wc * 64 + j * 16 + lm;
#pragma unroll
      for (int r = 0; r < 4; ++r)
        Y[(size_t)(rg0 + r) * 8192 + cg] = f2bf(acc[i][j][r]);
    }
  }
}

// ---------------- 128x(32*NJ) 2-phase GEMM (psq + final) ------------------

template <int MODE, int NJ>
__global__ __launch_bounds__(256)
void gemm_kernel(unsigned short* __restrict__ ws,
                 const float* __restrict__ bias,
                 float* __restrict__ dout) {
  __shared__ short At[128 * 64];
  __shared__ short Bt[32 * NJ * 64];

  const int tid = threadIdx.x;
  const int l   = tid & 63;
  const int w   = tid >> 6;
  const int wr  = w >> 1, wc = w & 1;

  int bm, bn, s = 0;
  const unsigned short* A = nullptr;
  const unsigned short* B;
  int KT;
  if constexpr (MODE == 0) {
    bm = blockIdx.x; bn = blockIdx.y; s = blockIdx.z;
    A = ws + OFF_PSTK + (size_t)(2 * s) * MB1;
    B = ws + OFF_SUPT + (size_t)s * MB1;
    KT = 16;
  } else {
    bm = blockIdx.x; bn = 0;
    B = ws + OFF_W2T;
    KT = 10;
  }

  const int subrow = l >> 3;
  const int koff   = (((l & 7) << 3) ^ (subrow << 3));

  f32x4 acc[4][NJ] = {};

  for (int kt = 0; kt < KT; ++kt) {
#pragma unroll
    for (int c = 0; c < 4; ++c) {
      int chunk = w * 4 + c;
      int rowl  = chunk * 8 + subrow;
      const unsigned short* gp;
      if constexpr (MODE == 2) {
        int rg = bm * 128 + rowl;
        const unsigned short* base =
            (kt < 2) ? (ws + OFF_X0NF)
                     : (ws + OFF_XNF + (size_t)((kt >> 1) - 1) * SZ_MAT);
        gp = base + (size_t)(rg >> 6) * 8192 + (size_t)(rg & 63) * 128 +
             (kt & 1) * 64 + koff;
      } else {
        gp = A + (size_t)(bm * 128 + rowl) * 1024 + kt * 64 + koff;
      }
      GLD16(gp, &At[chunk * 512]);
    }
#pragma unroll
    for (int c = 0; c < NJ; ++c) {
      int chunk = w * NJ + c;
      int rowl  = chunk * 8 + subrow;
      const unsigned short* gp;
      if constexpr (MODE == 2) {
        gp = B + (size_t)rowl * 640 + kt * 64 + koff;
      } else {
        gp = B + (size_t)(bn * (32 * NJ) + rowl) * 1024 + kt * 64 + koff;
      }
      GLD16(gp, &Bt[chunk * 512]);
    }
    __syncthreads();

#pragma unroll
    for (int kk = 0; kk < 2; ++kk) {
      bf16x8 af[4], bfv[NJ];
#pragma unroll
      for (int i = 0; i < 4; ++i) {
        int row = wr * 64 + i * 16 + (l & 15);
        int off = row * 64 + ((kk * 32 + ((l >> 4) << 3)) ^ ((row & 7) << 3));
        af[i] = *(const bf16x8*)&At[off];
      }
#pragma unroll
      for (int j = 0; j < NJ; ++j) {
        int row = wc * (16 * NJ) + j * 16 + (l & 15);
        int off = row * 64 + ((kk * 32 + ((l >> 4) << 3)) ^ ((row & 7) << 3));
        bfv[j] = *(const bf16x8*)&Bt[off];
      }
#pragma unroll
      for (int i = 0; i < 4; ++i)
#pragma unroll
        for (int j = 0; j < NJ; ++j)
          acc[i][j] = __builtin_amdgcn_mfma_f32_16x16x32_bf16(af[i], bfv[j],
                                                              acc[i][j], 0, 0, 0);
    }
    __syncthreads();
  }

  if constexpr (MODE == 0) {
    unsigned short* P = ws + OFF_PSTK + (size_t)(2 * s + 1) * MB1;
#pragma unroll
    for (int i = 0; i < 4; ++i) {
      int rg0 = bm * 128 + wr * 64 + i * 16 + ((l >> 4) << 2);
#pragma unroll
      for (int j = 0; j < NJ; ++j) {
        int cg = bn * (32 * NJ) + wc * (16 * NJ) + j * 16 + (l & 15);
#pragma unroll
        for (int r = 0; r < 4; ++r) {
          int rg = rg0 + r;
          float v = 2.0f * acc[i][j][r] - (rg == cg ? 1.0f : 0.0f);
          P[(size_t)rg * 1024 + cg] = f2bf(v);
        }
      }
    }
  } else {
#pragma unroll
    for (int i = 0; i < 4; ++i) {
      int rg0 = bm * 128 + wr * 64 + i * 16 + ((l >> 4) << 2);   // r = n*64+b
#pragma unroll
      for (int j = 0; j < NJ; ++j) {
        int cg = wc * 64 + j * 16 + (l & 15);                    // o
        float bv = bias[cg];
#pragma unroll
        for (int r = 0; r < 4; ++r) {
          int rg = rg0 + r;
          int drow = ((rg & 63) << 10) | (rg >> 6);              // b*1024 + n
          dout[(size_t)drow * 128 + cg] = acc[i][j][r] + bv;
        }
      }
    }
  }
}

// ---------------- launcher ----------------

extern "C" void kernel_launch(void* const* d_in, const int* in_sizes, int n_in,
                              void* d_out, int out_size, void* d_ws, size_t ws_size,
                              hipStream_t stream) {
  (void)in_sizes; (void)n_in; (void)out_size; (void)ws_size;
  const float* supports = (const float*)d_in[0];
  const float* inputs   = (const float*)d_in[1];
  const float* state    = (const float*)d_in[2];
  const float* weight   = (const float*)d_in[3];
  const float* bias     = (const float*)d_in[4];
  float* out = (float*)d_out;
  unsigned short* ws = (unsigned short*)d_ws;

  prep_kernel<<<4928, 256, 0, stream>>>(supports, weight, inputs, state, ws);
  gemm_kernel<0, 1><<<dim3(8, 32, 2), 256, 0, stream>>>(ws, bias, out);  // P1,P3
  gemm8_kernel<<<512, 512, 131072, stream>>>(ws);                        // Y
  gemm_kernel<2, 4><<<512, 256, 0, stream>>>(ws, bias, out);             // out
}

// Round 6
// 113.654 us; speedup vs baseline: 1.2211x; 1.2211x over previous
//
#include <hip/hip_runtime.h>
#include <hip/hip_bf16.h>

// DiffusionGraphConv on MI355X (gfx950), bf16 MFMA pipeline, round 6.
//
// Pipeline (3 launches):
//   prep (fused): cvt_sup | sup_t(from f32) | w2t | pack
//   psq  (128x32 2-phase GEMM): Pstack = [A1; 2A1^2-I; A2; 2A2^2-I]
//   mega (2-phase GEMM, fused): per band m'=1..4:
//            Yt[(b,f)][n] = x0t_tile @ Pband^T      (K=1024, 16 kt)
//            Yt -> LDS Bt2[n][f] (bf16, swizzled)   (no HBM round-trip!)
//            out^T[o][n] += w2t_band @ Bt2          (K=128, 2 kt)
//        then out^T += w2t_m0 @ X0nf-tile, + bias -> d_out
//
// Y never touches HBM: saves 64MB Y write + the entire final-GEMM pass
// (114MB, ~19us) + one launch.  LDS 64KB -> 2 blocks/CU (keeps the R4
// wave-overlap regime; the 1-block/CU 8-phase attempts of R3/R5 are dead).
//
// ws layout (bf16 elems):
//   PSTK 4M | SUPT 2M | X0T 8M | X0NF 8M | (XNF unused) | W2T 80K

typedef short bf16x8  __attribute__((ext_vector_type(8)));
typedef short short4v __attribute__((ext_vector_type(4)));
typedef float f32x4   __attribute__((ext_vector_type(4)));

constexpr size_t MB1    = 1024ull * 1024ull;
constexpr size_t SZ_MAT = 8192ull * 1024ull;
constexpr size_t OFF_PSTK = 0;
constexpr size_t OFF_SUPT = 4 * MB1;
constexpr size_t OFF_X0T  = 6 * MB1;
constexpr size_t OFF_X0NF = OFF_X0T  + SZ_MAT;
constexpr size_t OFF_XNF  = OFF_X0NF + SZ_MAT;
constexpr size_t OFF_W2T  = OFF_XNF  + 4 * SZ_MAT;

__device__ __forceinline__ unsigned short f2bf(float x) {
  union { float f; unsigned int u; } v; v.f = x;
  unsigned int r = v.u + 0x7fffu + ((v.u >> 16) & 1u);   // RNE
  return (unsigned short)(r >> 16);
}

#define GLD16(gp, lp)                                                         \
  __builtin_amdgcn_global_load_lds(                                           \
      (const __attribute__((address_space(1))) unsigned int*)(gp),            \
      (__attribute__((address_space(3))) unsigned int*)(lp), 16, 0, 0)

// ---------------- fused prep kernel (unchanged from round 4) --------------

__global__ __launch_bounds__(256)
void prep_kernel(const float* __restrict__ sup,
                 const float* __restrict__ weight,
                 const float* __restrict__ inputs,
                 const float* __restrict__ state,
                 unsigned short* __restrict__ ws) {
  __shared__ unsigned short tile[64][65];
  int bid = blockIdx.x;
  int tl  = threadIdx.x;

  if (bid < 2048) {                       // ---- cvt_sup
    size_t t = (size_t)bid * 256 + tl;
    const float4* src = (const float4*)sup;
    float4 v = src[t];
    size_t e = t * 4;
    size_t s = e >> 20;
    size_t r = e & (MB1 - 1);
    short4v o; o[0] = (short)f2bf(v.x); o[1] = (short)f2bf(v.y);
    o[2] = (short)f2bf(v.z); o[3] = (short)f2bf(v.w);
    *(short4v*)&ws[OFF_PSTK + 2 * s * MB1 + r] = o;
  } else if (bid < 2560) {                // ---- sup_t (from f32 source)
    int i = bid - 2048;
    int nt = i & 15, mt = (i >> 4) & 15, s = i >> 8;
    const float* A = sup + (size_t)s * MB1;
    unsigned short* AT = ws + OFF_SUPT + (size_t)s * MB1;
    int cl = tl & 63, rg = tl >> 6;
#pragma unroll 4
    for (int rr = 0; rr < 16; ++rr) {
      int rl = rr * 4 + rg;
      tile[rl][cl] = f2bf(A[(size_t)(nt * 64 + rl) * 1024 + mt * 64 + cl]);
    }
    __syncthreads();
#pragma unroll 4
    for (int rr = 0; rr < 16; ++rr) {
      int ml = rr * 4 + rg;
      AT[(size_t)(mt * 64 + ml) * 1024 + nt * 64 + cl] = tile[cl][ml];
    }
  } else if (bid < 2880) {                // ---- w2t
    int t = (bid - 2560) * 256 + tl;
    int o = t / 640, k = t % 640;
    int m = k >> 7, f = k & 127;
    ws[OFF_W2T + t] = f2bf(weight[(f * 5 + m) * 128 + o]);
  } else {                                // ---- pack
    int i = bid - 2880;
    int b = i & 63, nt = (i >> 6) & 15, ft = i >> 10;
    const float* src = ft ? state : inputs;
    unsigned short* x0t  = ws + OFF_X0T;
    unsigned short* x0nf = ws + OFF_X0NF;
    int fl = tl & 63, nr = tl >> 6;
#pragma unroll 4
    for (int rr = 0; rr < 16; ++rr) {
      int n_loc = rr * 4 + nr;
      float v = src[(size_t)b * 65536 + (size_t)(nt * 64 + n_loc) * 64 + fl];
      unsigned short bv = f2bf(v);
      tile[n_loc][fl] = bv;
      x0nf[(size_t)(nt * 64 + n_loc) * 8192 + b * 128 + ft * 64 + fl] = bv;
    }
    __syncthreads();
#pragma unroll 4
    for (int rr = 0; rr < 16; ++rr) {
      int f_loc = rr * 4 + nr;
      x0t[(size_t)(b * 128 + ft * 64 + f_loc) * 1024 + nt * 64 + fl] =
          tile[fl][f_loc];
    }
  }
}

// ---------------- mega kernel: diffusion + output GEMM fused --------------
// 256 thr (4 waves 2x2), block tile 128(bf) x 128(n).
// LDS (elems): A-stage [0,8192) | B-stage [8192,16384) | Bt2 [16384,32768)
// Bt2: [n 128 rows][f 128], 16B-granule XOR swizzle: granule ^= (n&7).

__global__ __launch_bounds__(256, 2)
void mega_kernel(unsigned short* __restrict__ ws,
                 const float* __restrict__ bias,
                 float* __restrict__ dout) {
  extern __shared__ unsigned short lds[];   // 65536 B via launch config

  const unsigned short* X0T = ws + OFF_X0T;    // [(b,f)=8192][1024]
  const unsigned short* X0N = ws + OFF_X0NF;   // [n=1024][(b,f)=8192]
  const unsigned short* W2  = ws + OFF_W2T;    // [o=128][640]

  const int tid = threadIdx.x;
  const int l   = tid & 63;
  const int w   = tid >> 6;
  const int wr  = w >> 1, wc = w & 1;
  const int lm  = l & 15, q = l >> 4;

  // grid 512 = 64 bf-tiles x 8 n-tiles; XCD owns an 8x8 rect (bf-range).
  int bid = blockIdx.x;
  int xcd = bid & 7, idx = bid >> 3;
  const int bm = xcd * 8 + (idx & 7);    // bf-tile = batch b (0..63)
  const int bn = idx >> 3;               // n-tile (0..7)

  // staging constants (proven R4 pattern): chunk = 8 rows x 64k.
  const int subrow = l >> 3;
  const int koff   = (((l & 7) << 3) ^ (subrow << 3));

  auto stage_x0t = [&](int kt) {         // A-buf <- x0t rows bf-tile
#pragma unroll
    for (int c = 0; c < 4; ++c) {
      int chunk = w * 4 + c, rowl = chunk * 8 + subrow;
      const unsigned short* gp =
          X0T + (size_t)(bm * 128 + rowl) * 1024 + kt * 64 + koff;
      GLD16(gp, &lds[chunk * 512]);
    }
  };
  auto stage_P = [&](int band, int kt) { // B-buf <- Pstack band rows n-tile
#pragma unroll
    for (int c = 0; c < 4; ++c) {
      int chunk = w * 4 + c, rowl = chunk * 8 + subrow;
      const unsigned short* gp = ws + OFF_PSTK + (size_t)band * MB1 +
                                 (size_t)(bn * 128 + rowl) * 1024 + kt * 64 + koff;
      GLD16(gp, &lds[8192 + chunk * 512]);
    }
  };
  auto stage_w2 = [&](int m, int kt2) {  // A-buf <- w2t rows o, k-slice m
#pragma unroll
    for (int c = 0; c < 4; ++c) {
      int chunk = w * 4 + c, rowl = chunk * 8 + subrow;
      const unsigned short* gp =
          W2 + (size_t)rowl * 640 + m * 128 + kt2 * 64 + koff;
      GLD16(gp, &lds[chunk * 512]);
    }
  };
  auto stage_x0n = [&](int kt2) {        // B-buf <- x0nf rows n-tile, b=bm
#pragma unroll
    for (int c = 0; c < 4; ++c) {
      int chunk = w * 4 + c, rowl = chunk * 8 + subrow;
      const unsigned short* gp =
          X0N + (size_t)(bn * 128 + rowl) * 8192 + bm * 128 + kt2 * 64 + koff;
      GLD16(gp, &lds[8192 + chunk * 512]);
    }
  };

  f32x4 oacc[4][4] = {};

  for (int band = 0; band < 4; ++band) {
    // ---- Yt tile = x0t_tile @ Pband^T  (K=1024) ----
    f32x4 yacc[4][4] = {};
    for (int kt = 0; kt < 16; ++kt) {
      stage_x0t(kt);
      stage_P(band, kt);
      __syncthreads();
#pragma unroll
      for (int kk = 0; kk < 2; ++kk) {
        bf16x8 af[4], bfv[4];
#pragma unroll
        for (int i = 0; i < 4; ++i) {
          int row = wr * 64 + i * 16 + lm;
          int off = row * 64 + ((kk * 32 + (q << 3)) ^ ((row & 7) << 3));
          af[i] = *(const bf16x8*)&lds[off];
        }
#pragma unroll
        for (int j = 0; j < 4; ++j) {
          int row = wc * 64 + j * 16 + lm;
          int off = 8192 + row * 64 + ((kk * 32 + (q << 3)) ^ ((row & 7) << 3));
          bfv[j] = *(const bf16x8*)&lds[off];
        }
#pragma unroll
        for (int i = 0; i < 4; ++i)
#pragma unroll
          for (int j = 0; j < 4; ++j)
            yacc[i][j] = __builtin_amdgcn_mfma_f32_16x16x32_bf16(
                af[i], bfv[j], yacc[i][j], 0, 0, 0);
      }
      __syncthreads();
    }

    // ---- Yt -> Bt2[n][f] bf16 (swizzled; 8B contiguous runs) ----
#pragma unroll
    for (int i = 0; i < 4; ++i) {
      int f0 = wr * 64 + i * 16 + q * 4;               // 4 consecutive f
#pragma unroll
      for (int j = 0; j < 4; ++j) {
        int n = wc * 64 + j * 16 + lm;
        short4v pk;
#pragma unroll
        for (int r = 0; r < 4; ++r) pk[r] = (short)f2bf(yacc[i][j][r]);
        *(short4v*)&lds[16384 + n * 128 + (((f0 >> 3) ^ (n & 7)) << 3) +
                        (f0 & 7)] = pk;
      }
    }
    __syncthreads();

    // ---- out^T += w2t[band m'] @ Bt2  (K=128, 2 kt) ----
#pragma unroll
    for (int kt2 = 0; kt2 < 2; ++kt2) {
      stage_w2(band + 1, kt2);
      __syncthreads();
#pragma unroll
      for (int kk = 0; kk < 2; ++kk) {
        bf16x8 af[4], bfv[4];
#pragma unroll
        for (int i = 0; i < 4; ++i) {
          int row = wr * 64 + i * 16 + lm;             // o
          int off = row * 64 + ((kk * 32 + (q << 3)) ^ ((row & 7) << 3));
          af[i] = *(const bf16x8*)&lds[off];
        }
#pragma unroll
        for (int j = 0; j < 4; ++j) {
          int n = wc * 64 + j * 16 + lm;
          int g = kt2 * 8 + kk * 4 + q;                // f granule
          bfv[j] = *(const bf16x8*)&lds[16384 + n * 128 + ((g ^ (n & 7)) << 3)];
        }
#pragma unroll
        for (int i = 0; i < 4; ++i)
#pragma unroll
          for (int j = 0; j < 4; ++j)
            oacc[i][j] = __builtin_amdgcn_mfma_f32_16x16x32_bf16(
                af[i], bfv[j], oacc[i][j], 0, 0, 0);
      }
      __syncthreads();
    }
  }

  // ---- m=0 term: out^T += w2t[m=0] @ X0nf-tile  (K=128, 2 kt) ----
#pragma unroll
  for (int kt2 = 0; kt2 < 2; ++kt2) {
    stage_w2(0, kt2);
    stage_x0n(kt2);
    __syncthreads();
#pragma unroll
    for (int kk = 0; kk < 2; ++kk) {
      bf16x8 af[4], bfv[4];
#pragma unroll
      for (int i = 0; i < 4; ++i) {
        int row = wr * 64 + i * 16 + lm;               // o
        int off = row * 64 + ((kk * 32 + (q << 3)) ^ ((row & 7) << 3));
        af[i] = *(const bf16x8*)&lds[off];
      }
#pragma unroll
      for (int j = 0; j < 4; ++j) {
        int row = wc * 64 + j * 16 + lm;               // n
        int off = 8192 + row * 64 + ((kk * 32 + (q << 3)) ^ ((row & 7) << 3));
        bfv[j] = *(const bf16x8*)&lds[off];
      }
#pragma unroll
      for (int i = 0; i < 4; ++i)
#pragma unroll
        for (int j = 0; j < 4; ++j)
          oacc[i][j] = __builtin_amdgcn_mfma_f32_16x16x32_bf16(
              af[i], bfv[j], oacc[i][j], 0, 0, 0);
    }
    __syncthreads();
  }

  // ---- epilogue: out[b][n*128+o] = out^T[o][n] + bias[o] ----
#pragma unroll
  for (int i = 0; i < 4; ++i) {
    int o0 = wr * 64 + i * 16 + q * 4;                 // 4 consecutive o
    float4 bv = *(const float4*)&bias[o0];
#pragma unroll
    for (int j = 0; j < 4; ++j) {
      int n = bn * 128 + wc * 64 + j * 16 + lm;
      float4 v;
      v.x = oacc[i][j][0] + bv.x;
      v.y = oacc[i][j][1] + bv.y;
      v.z = oacc[i][j][2] + bv.z;
      v.w = oacc[i][j][3] + bv.w;
      *(float4*)&dout[(size_t)bm * 131072 + (size_t)n * 128 + o0] = v;
    }
  }
}

// ---------------- psq: 128x32 2-phase GEMM (unchanged R4 MODE 0) ----------

__global__ __launch_bounds__(256)
void psq_kernel(unsigned short* __restrict__ ws) {
  __shared__ short At[128 * 64];
  __shared__ short Bt[32 * 64];

  const int tid = threadIdx.x;
  const int l   = tid & 63;
  const int w   = tid >> 6;
  const int wr  = w >> 1, wc = w & 1;

  const int bm = blockIdx.x, bn = blockIdx.y, s = blockIdx.z;
  const unsigned short* A = ws + OFF_PSTK + (size_t)(2 * s) * MB1;
  const unsigned short* B = ws + OFF_SUPT + (size_t)s * MB1;

  const int subrow = l >> 3;
  const int koff   = (((l & 7) << 3) ^ (subrow << 3));

  f32x4 acc[4][1] = {};

  for (int kt = 0; kt < 16; ++kt) {
#pragma unroll
    for (int c = 0; c < 4; ++c) {
      int chunk = w * 4 + c, rowl = chunk * 8 + subrow;
      GLD16(A + (size_t)(bm * 128 + rowl) * 1024 + kt * 64 + koff,
            &At[chunk * 512]);
    }
    {
      int chunk = w, rowl = chunk * 8 + subrow;
      GLD16(B + (size_t)(bn * 32 + rowl) * 1024 + kt * 64 + koff,
            &Bt[chunk * 512]);
    }
    __syncthreads();

#pragma unroll
    for (int kk = 0; kk < 2; ++kk) {
      bf16x8 af[4], bfv;
#pragma unroll
      for (int i = 0; i < 4; ++i) {
        int row = wr * 64 + i * 16 + (l & 15);
        int off = row * 64 + ((kk * 32 + ((l >> 4) << 3)) ^ ((row & 7) << 3));
        af[i] = *(const bf16x8*)&At[off];
      }
      {
        int row = wc * 16 + (l & 15);
        int off = row * 64 + ((kk * 32 + ((l >> 4) << 3)) ^ ((row & 7) << 3));
        bfv = *(const bf16x8*)&Bt[off];
      }
#pragma unroll
      for (int i = 0; i < 4; ++i)
        acc[i][0] = __builtin_amdgcn_mfma_f32_16x16x32_bf16(af[i], bfv,
                                                            acc[i][0], 0, 0, 0);
    }
    __syncthreads();
  }

  unsigned short* P = ws + OFF_PSTK + (size_t)(2 * s + 1) * MB1;
#pragma unroll
  for (int i = 0; i < 4; ++i) {
    int rg0 = bm * 128 + wr * 64 + i * 16 + ((l >> 4) << 2);
    int cg  = bn * 32 + wc * 16 + (l & 15);
#pragma unroll
    for (int r = 0; r < 4; ++r) {
      int rg = rg0 + r;
      float v = 2.0f * acc[i][0][r] - (rg == cg ? 1.0f : 0.0f);
      P[(size_t)rg * 1024 + cg] = f2bf(v);
    }
  }
}

// ---------------- launcher ----------------

extern "C" void kernel_launch(void* const* d_in, const int* in_sizes, int n_in,
                              void* d_out, int out_size, void* d_ws, size_t ws_size,
                              hipStream_t stream) {
  (void)in_sizes; (void)n_in; (void)out_size; (void)ws_size;
  const float* supports = (const float*)d_in[0];
  const float* inputs   = (const float*)d_in[1];
  const float* state    = (const float*)d_in[2];
  const float* weight   = (const float*)d_in[3];
  const float* bias     = (const float*)d_in[4];
  float* out = (float*)d_out;
  unsigned short* ws = (unsigned short*)d_ws;

  prep_kernel<<<4928, 256, 0, stream>>>(supports, weight, inputs, state, ws);
  psq_kernel<<<dim3(8, 32, 2), 256, 0, stream>>>(ws);
  mega_kernel<<<512, 256, 65536, stream>>>(ws, bias, out);
}